// Round 6
// baseline (176.188 us; speedup 1.0000x reference)
//
#include <hip/hip_runtime.h>
#include <math.h>

// B=4, T=512, IDIM=128, HDIM=1024, CDIM=256
#define NBLK  2048            // one row per block, 2 waves per block
#define NITER 4
#define IGNORE_OUT 10000.0f
#define LOG2E 1.44269504088896340736f

__device__ __forceinline__ float readlanef(float v, int lane){
  return __int_as_float(__builtin_amdgcn_readlane(__float_as_int(v), lane));
}

// ---- DPP wave primitives (gfx9 ladder: row_shr 1/2/4/8, bcast15->rows1,3, bcast31->rows2,3) ----
__device__ __forceinline__ float waveScanInc(float v){
  v += __int_as_float(__builtin_amdgcn_update_dpp(0, __float_as_int(v), 0x111, 0xF, 0xF, true));
  v += __int_as_float(__builtin_amdgcn_update_dpp(0, __float_as_int(v), 0x112, 0xF, 0xF, true));
  v += __int_as_float(__builtin_amdgcn_update_dpp(0, __float_as_int(v), 0x114, 0xF, 0xF, true));
  v += __int_as_float(__builtin_amdgcn_update_dpp(0, __float_as_int(v), 0x118, 0xF, 0xF, true));
  v += __int_as_float(__builtin_amdgcn_update_dpp(0, __float_as_int(v), 0x142, 0xA, 0xF, true));
  v += __int_as_float(__builtin_amdgcn_update_dpp(0, __float_as_int(v), 0x143, 0xC, 0xF, true));
  return v;                                // lane l = sum of lanes 0..l
}
__device__ __forceinline__ float waveSum(float v){
  return readlanef(waveScanInc(v), 63);
}
__device__ __forceinline__ void waveArgmax(float &v, int &i){
#define AMSTEP(ctrl, rm) { \
    float ov = __int_as_float(__builtin_amdgcn_update_dpp(__float_as_int(v), __float_as_int(v), ctrl, rm, 0xF, false)); \
    int   oi = __builtin_amdgcn_update_dpp(i, i, ctrl, rm, 0xF, false); \
    bool take = (ov > v) || (ov == v && oi < i); \
    v = take ? ov : v; i = take ? oi : i; }
  AMSTEP(0x111, 0xF) AMSTEP(0x112, 0xF) AMSTEP(0x114, 0xF)
  AMSTEP(0x118, 0xF) AMSTEP(0x142, 0xA) AMSTEP(0x143, 0xC)
#undef AMSTEP
  v = readlanef(v, 63);
  i = __builtin_amdgcn_readlane(i, 63);
}
// paired gather: a = vec[idx], b = vec[idx+64] (0 outside [0,128)); 2 bpermutes total
__device__ __forceinline__ void gatherPair(float v0, float v1, int idx, float &a, float &b){
  int c = idx & 63;
  float g0 = __shfl(v0, c, 64);
  float g1 = __shfl(v1, c, 64);
  a = ((unsigned)idx < 128u) ? ((idx & 64) ? g1 : g0) : 0.f;
  int idx2 = idx + 64;
  b = ((unsigned)idx2 < 128u) ? ((idx2 & 64) ? g1 : g0) : 0.f;
}

// ---------- prep kernel (r5 version: 512 threads, K-quarter split, LDS combine) ----------
__global__ __launch_bounds__(512)
void prepK(const float* __restrict__ w1, const float* __restrict__ b1,
           const float* __restrict__ w2, const float* __restrict__ b2,
           float* __restrict__ M4, float* __restrict__ biasT, int* __restrict__ ticket){
  const int blk = blockIdx.x;
  const int tid = threadIdx.x;
  const int u = tid & 127, q = tid >> 7;   // u = output-row/col, q = K-quarter 0..3
  __shared__ float part[512];
  if (blk < 512){
    int i = blk >> 7, o = blk & 127;
    const float* w1p = w1 + (i * 256 + q * 64) * 128 + u;   // coalesced over d=u
    const float* w2p = w2 + o * 1024 + i * 256 + q * 64;    // wave-uniform
    float a0 = 0.f, a1 = 0.f, a2 = 0.f, a3 = 0.f;
    #pragma unroll
    for (int c = 0; c < 64; c += 4){
      a0 = fmaf(w1p[(c + 0) * 128], w2p[c + 0], a0);
      a1 = fmaf(w1p[(c + 1) * 128], w2p[c + 1], a1);
      a2 = fmaf(w1p[(c + 2) * 128], w2p[c + 2], a2);
      a3 = fmaf(w1p[(c + 3) * 128], w2p[c + 3], a3);
    }
    part[tid] = (a0 + a1) + (a2 + a3);
    __syncthreads();
    if (q == 0)
      M4[i * 16384 + (u >> 2) * 512 + o * 4 + (u & 3)] =
          (part[u] + part[128 + u]) + (part[256 + u] + part[384 + u]);
  } else if (blk < 516){
    int i = blk - 512;
    const float* w2p = w2 + u * 1024 + i * 256 + q * 64;
    const float* b1p = b1 + i * 256 + q * 64;
    float a0 = (q == 0) ? b2[u] : 0.f, a1 = 0.f, a2 = 0.f, a3 = 0.f;
    #pragma unroll
    for (int c = 0; c < 64; c += 4){
      a0 = fmaf(b1p[c + 0], w2p[c + 0], a0);
      a1 = fmaf(b1p[c + 1], w2p[c + 1], a1);
      a2 = fmaf(b1p[c + 2], w2p[c + 2], a2);
      a3 = fmaf(b1p[c + 3], w2p[c + 3], a3);
    }
    part[tid] = (a0 + a1) + (a2 + a3);
    __syncthreads();
    if (q == 0)
      biasT[i * 128 + u] = (part[u] + part[128 + u]) + (part[256 + u] + part[384 + u]);
  } else {
    if (tid == 0) *ticket = 0;
  }
}

// M-group load macro — NAMED float4 scalars only (no arrays: spill-proof).
#define MLD(d0, d1, d2, d3, gg) \
  d0 = Mp[((gg) * 4 + 0) * 128 + u]; d1 = Mp[((gg) * 4 + 1) * 128 + u]; \
  d2 = Mp[((gg) * 4 + 2) * 128 + u]; d3 = Mp[((gg) * 4 + 3) * 128 + u];
// consume group (k = 16g..16g+15) with UNIFORM-LDS broadcasts of x_attn (no readlane):
// accumulation order identical to the readlane version (m0 row pairs with XW[4g], etc.)
#define MFM(m0, m1, m2, m3, g) { \
    float4 xA = XW[4*(g)+0], xB = XW[4*(g)+1], xC = XW[4*(g)+2], xD = XW[4*(g)+3]; \
    a0 = fmaf((m0).x, xA.x, a0); a0 = fmaf((m0).y, xA.y, a0); \
    a0 = fmaf((m0).z, xA.z, a0); a0 = fmaf((m0).w, xA.w, a0); \
    a1 = fmaf((m1).x, xB.x, a1); a1 = fmaf((m1).y, xB.y, a1); \
    a1 = fmaf((m1).z, xB.z, a1); a1 = fmaf((m1).w, xB.w, a1); \
    a2 = fmaf((m2).x, xC.x, a2); a2 = fmaf((m2).y, xC.y, a2); \
    a2 = fmaf((m2).z, xC.z, a2); a2 = fmaf((m2).w, xC.w, a2); \
    a3 = fmaf((m3).x, xD.x, a3); a3 = fmaf((m3).y, xD.y, a3); \
    a3 = fmaf((m3).z, xD.z, a3); a3 = fmaf((m3).w, xD.w, a3); }

// ---------- main kernel ----------
// wave w handles shift-pair t = 64w + l; t index per thread = u. A = 255-u.
// Window: ydlin[k] (k in [128,384)) duplicated y_res; 4 shift-aligned copies
//   ydc[r][k] = ydlin[k+r]  ->  lane reads copy r=A&3 at 16B-aligned base A&~3 via b128.
//   Stride 392 (%32 == 8): each 8-lane group of a b128 read covers all 32 banks once.
// x broadcasts come from per-wave LDS buffers (uniform-address b128 = conflict-free
// broadcast) instead of v_readlane: same values, same fma order, no SGPR hazards.
__global__ __launch_bounds__(128, 4)
void mainK(const float* __restrict__ x, const float* __restrict__ y,
           const float* __restrict__ M4, const float* __restrict__ biasT,
           unsigned long long* __restrict__ partials, int* __restrict__ ticket,
           float* __restrict__ out){
  __shared__ float ydc[4][392];   // 4 shift-aligned y-window copies (cross-wave)
  __shared__ float xs[2][128];    // per-wave x_res broadcast source
  __shared__ float xw[2][128];    // per-wave x_attn broadcast source
  __shared__ float sVal[2];
  __shared__ int   sIdx[2];
  __shared__ float sL[2], sC[2];
  __shared__ int   sOld;

  const int u = threadIdx.x;               // 0..127 ; u = 64w + l = owned element / output
  const int l = u & 63;
  const int w = u >> 6;
  const long base = (long)blockIdx.x * 128;

  float xlo = x[base + l], xhi = x[base + 64 + l];
  float ylo = y[base + l], yhi = y[base + 64 + l];
  const float yOwn0 = w ? yhi : ylo;
  const bool mOwn = (yOwn0 == IGNORE_OUT);
  float cnt = mOwn ? 0.f : 1.f;
  float lossAcc = 0.f;

  #pragma unroll
  for (int r = 0; r < 4; ++r){ ydc[r][128 + u - r] = yOwn0; ydc[r][256 + u - r] = yOwn0; }
  __syncthreads();

  const int A = 255 - u;
  const float4* wrow = (const float4*)&ydc[A & 3][A & ~3];  // 16B-aligned (1568B rows)
  const float4* XS = (const float4*)&xs[w][0];
  const float4* XW = (const float4*)&xw[w][0];

  for (int i = 0; i < NITER; ++i){
    const float4* Mp = (const float4*)(M4 + (size_t)i * 16384);

    // publish per-wave x_res copy (same-wave RAW via lgkmcnt; no barrier)
    xs[w][l] = xlo; xs[w][64 + l] = xhi;

    // ---- window-norm prefix at t = 64w+l (DPP scan + DPP sums; zero DS) ----
    float own2 = w ? xhi * xhi : xlo * xlo;
    float oth2 = w ? xlo * xlo : xhi * xhi;
    float v = waveScanInc(own2);
    float osum  = waveSum(oth2);
    float total = readlanef(v, 63) + osum;
    float pref_t = w ? (v + osum) : v;     // inclusive prefix of x^2 at index t
    float ny2 = waveSum(ylo * ylo + yhi * yhi);

    // ---- corr: 32 aligned ds_read_b128 window reads + 32 uniform b128 x broadcasts;
    //      4-way-split full sums + 4-way-split masked prefix (same order as r3) ----
    float s0=0.f,s1=0.f,s2=0.f,s3=0.f;     // first half  (j=0..63)  full sum
    float t0=0.f,t1=0.f,t2=0.f,t3=0.f;     // second half (j=64..127) full sum
    float p0=0.f,p1=0.f,p2=0.f,p3=0.f;     // masked prefix over own half
    if (w == 0){                           // t = l: prefix lives in first half
      #pragma unroll
      for (int m = 0; m < 16; ++m){
        float4 wv = wrow[m], xv = XS[m];
        const int jb = 4 * m;
        s0 = fmaf(wv.x, xv.x, s0); s1 = fmaf(wv.y, xv.y, s1);
        s2 = fmaf(wv.z, xv.z, s2); s3 = fmaf(wv.w, xv.w, s3);
        p0 = fmaf((l >= jb    ) ? wv.x : 0.f, xv.x, p0);
        p1 = fmaf((l >= jb + 1) ? wv.y : 0.f, xv.y, p1);
        p2 = fmaf((l >= jb + 2) ? wv.z : 0.f, xv.z, p2);
        p3 = fmaf((l >= jb + 3) ? wv.w : 0.f, xv.w, p3);
      }
      #pragma unroll
      for (int m = 16; m < 32; ++m){
        float4 wv = wrow[m], xv = XS[m];
        t0 = fmaf(wv.x, xv.x, t0); t1 = fmaf(wv.y, xv.y, t1);
        t2 = fmaf(wv.z, xv.z, t2); t3 = fmaf(wv.w, xv.w, t3);
      }
    } else {                               // t = 64+l: first half all j<=t; prefix in second
      #pragma unroll
      for (int m = 0; m < 16; ++m){
        float4 wv = wrow[m], xv = XS[m];
        s0 = fmaf(wv.x, xv.x, s0); s1 = fmaf(wv.y, xv.y, s1);
        s2 = fmaf(wv.z, xv.z, s2); s3 = fmaf(wv.w, xv.w, s3);
      }
      #pragma unroll
      for (int m = 16; m < 32; ++m){
        float4 wv = wrow[m], xv = XS[m];
        const int jb = 4 * m - 64;
        t0 = fmaf(wv.x, xv.x, t0); t1 = fmaf(wv.y, xv.y, t1);
        t2 = fmaf(wv.z, xv.z, t2); t3 = fmaf(wv.w, xv.w, t3);
        p0 = fmaf((l >= jb    ) ? wv.x : 0.f, xv.x, p0);
        p1 = fmaf((l >= jb + 1) ? wv.y : 0.f, xv.y, p1);
        p2 = fmaf((l >= jb + 2) ? wv.z : 0.f, xv.z, p2);
        p3 = fmaf((l >= jb + 3) ? wv.w : 0.f, xv.w, p3);
      }
    }
    float Sh0 = (s0 + s1) + (s2 + s3);
    float Sh1 = (t0 + t1) + (t2 + t3);
    float P   = (p0 + p1) + (p2 + p3);
    float nt = Sh0 + Sh1;
    float n1 = w ? (Sh0 + P) : P;

    // ---- cosine sims via v_rsq; DPP argmax; cross-wave combine ----
    {
      bool yz = (ny2 == 0.f);
      float rNY = __builtin_amdgcn_rsqf(ny2);       // 1/||y||
      float nx2b = fmaxf(total - pref_t, 0.f);
      float s1v = (yz || pref_t == 0.f) ? 0.f : n1 * __builtin_amdgcn_rsqf(pref_t) * rNY;
      float s2v = (yz || nx2b  == 0.f) ? 0.f : (nt - n1) * __builtin_amdgcn_rsqf(nx2b) * rNY;
      if (u == 127) s2v = -INFINITY;       // shift 255 doesn't exist
      float bv = s1v; int bi = u;
      if (s2v > bv){ bv = s2v; bi = u + 128; }
      waveArgmax(bv, bi);
      if (l == 0){ sVal[w] = bv; sIdx[w] = bi; }
    }
    __syncthreads();                       // B1

    // ---- issue MLP groups 0,1 + bias: L2 latency hidden under argmax-combine +
    //      softmax + gathers; live ranges start HERE (never across corr/barriers) ----
    float4 A0, A1, A2, A3, B0, B1, B2, B3;
    MLD(A0, A1, A2, A3, 0)
    MLD(B0, B1, B2, B3, 1)
    float bias_i = biasT[i * 128 + u];

    int sstar;
    {
      float v0 = sVal[0], v1 = sVal[1];
      int   i0 = sIdx[0], i1 = sIdx[1];
      sstar = (v1 > v0 || (v1 == v0 && i1 < i0)) ? i1 : i0;
    }

    // ---- x_aug + detached softmax (hw exp2/rcp; paired gathers) ----
    float xa, xb;
    gatherPair(xlo, xhi, sstar + l - 127, xa, xb);
    float ea = __builtin_amdgcn_exp2f(xa * ylo * LOG2E);
    float eb = __builtin_amdgcn_exp2f(xb * yhi * LOG2E);
    float rse = __builtin_amdgcn_rcpf(waveSum(ea + eb));
    float wlo = xa * (ea * rse), whi = xb * (eb * rse);   // xatt

    // ---- x_res update (reverse shift, paired gather) ----
    {
      float ga, gb;
      gatherPair(wlo, whi, l + 127 - sstar, ga, gb);
      xlo -= ga; xhi -= gb;
    }

    // publish per-wave x_attn copy for uniform broadcasts (same-wave RAW)
    xw[w][l] = wlo; xw[w][64 + l] = whi;

    // ---- MLP: thread u -> output o = u; 2 rotating named-reg buffers,
    //      uniform-LDS x broadcasts; accumulation order identical to r3 ----
    float ye;
    {
      float a0 = 0.f, a1 = 0.f, a2 = 0.f, a3 = 0.f;
      MFM(A0, A1, A2, A3, 0)   MLD(A0, A1, A2, A3, 2)
      MFM(B0, B1, B2, B3, 1)   MLD(B0, B1, B2, B3, 3)
      MFM(A0, A1, A2, A3, 2)   MLD(A0, A1, A2, A3, 4)
      MFM(B0, B1, B2, B3, 3)   MLD(B0, B1, B2, B3, 5)
      MFM(A0, A1, A2, A3, 4)   MLD(A0, A1, A2, A3, 6)
      MFM(B0, B1, B2, B3, 5)   MLD(B0, B1, B2, B3, 7)
      MFM(A0, A1, A2, A3, 6)
      MFM(B0, B1, B2, B3, 7)
      ye = ((a0 + a1) + (a2 + a3)) + bias_i;
    }

    // ---- loss on owned element + publish new y_res (8 stores, 4 copies x 2) ----
    {
      float yOwn = w ? yhi : ylo;
      float df = ye - yOwn;
      if (!mOwn) lossAcc = fmaf(df, df, lossAcc);
      float yNew = yOwn - ye;
      #pragma unroll
      for (int r = 0; r < 4; ++r){ ydc[r][128 + u - r] = yNew; ydc[r][256 + u - r] = yNew; }
    }
    __syncthreads();                       // B2
    ylo = ydc[0][128 + l];                 // refresh register copies (copy 0 = ydlin)
    yhi = ydc[0][192 + l];
  }

  // ---- block loss/cnt, partial store + ticket; last block finalizes ----
  lossAcc = waveSum(lossAcc);
  cnt     = waveSum(cnt);
  if (l == 0){ sL[w] = lossAcc; sC[w] = cnt; }
  __syncthreads();
  if (u == 0){
    union { float2 f; unsigned long long v; } pk;
    pk.f.x = sL[0] + sL[1];
    pk.f.y = sC[0] + sC[1];
    __hip_atomic_store(&partials[blockIdx.x], pk.v, __ATOMIC_RELEASE, __HIP_MEMORY_SCOPE_AGENT);
    sOld = __hip_atomic_fetch_add(ticket, 1, __ATOMIC_ACQ_REL, __HIP_MEMORY_SCOPE_AGENT);
  }
  __syncthreads();
  if (sOld == NBLK - 1){
    float ls = 0.f, cs = 0.f;
    for (int g = u; g < NBLK; g += 128){
      union { float2 f; unsigned long long v; } pk;
      pk.v = __hip_atomic_load(&partials[g], __ATOMIC_ACQUIRE, __HIP_MEMORY_SCOPE_AGENT);
      ls += pk.f.x; cs += pk.f.y;
    }
    ls = waveSum(ls); cs = waveSum(cs);
    if (l == 0){ sL[w] = ls; sC[w] = cs; }
    __syncthreads();
    if (u == 0) out[0] = (sL[0] + sL[1]) / ((float)NITER * (sC[0] + sC[1]));
  }
}

extern "C" void kernel_launch(void* const* d_in, const int* in_sizes, int n_in,
                              void* d_out, int out_size, void* d_ws, size_t ws_size,
                              hipStream_t stream){
  const float* x  = (const float*)d_in[0];
  const float* y  = (const float*)d_in[1];
  const float* w1 = (const float*)d_in[2];
  const float* b1 = (const float*)d_in[3];
  const float* w2 = (const float*)d_in[4];
  const float* b2 = (const float*)d_in[5];
  float* out = (float*)d_out;

  // ws: [0,4) ticket ; [256, 256+256K) M4 ; +2K biasT ; +16K partials
  int*   ticket = (int*)d_ws;
  float* M4     = (float*)((char*)d_ws + 256);
  float* biasT  = (float*)((char*)d_ws + 256 + 4 * 128 * 128 * sizeof(float));
  unsigned long long* partials =
      (unsigned long long*)((char*)d_ws + 256 + 4 * 128 * 128 * sizeof(float) + 4 * 128 * sizeof(float));

  prepK<<<517, 512, 0, stream>>>(w1, b1, w2, b2, M4, biasT, ticket);
  mainK<<<NBLK, 128, 0, stream>>>(x, y, M4, biasT, partials, ticket, out);
}

// Round 7
// 160.768 us; speedup vs baseline: 1.0959x; 1.0959x over previous
//
#include <hip/hip_runtime.h>
#include <math.h>

// B=4, T=512, IDIM=128, HDIM=1024, CDIM=256
#define NBLK  2048            // one row per block, 4 waves per block
#define NITER 4
#define IGNORE_OUT 10000.0f
#define LOG2E 1.44269504088896340736f

__device__ __forceinline__ float readlanef(float v, int lane){
  return __int_as_float(__builtin_amdgcn_readlane(__float_as_int(v), lane));
}

// ---- DPP wave primitives (gfx9 ladder: row_shr 1/2/4/8, bcast15->rows1,3, bcast31->rows2,3) ----
__device__ __forceinline__ float waveScanInc(float v){
  v += __int_as_float(__builtin_amdgcn_update_dpp(0, __float_as_int(v), 0x111, 0xF, 0xF, true));
  v += __int_as_float(__builtin_amdgcn_update_dpp(0, __float_as_int(v), 0x112, 0xF, 0xF, true));
  v += __int_as_float(__builtin_amdgcn_update_dpp(0, __float_as_int(v), 0x114, 0xF, 0xF, true));
  v += __int_as_float(__builtin_amdgcn_update_dpp(0, __float_as_int(v), 0x118, 0xF, 0xF, true));
  v += __int_as_float(__builtin_amdgcn_update_dpp(0, __float_as_int(v), 0x142, 0xA, 0xF, true));
  v += __int_as_float(__builtin_amdgcn_update_dpp(0, __float_as_int(v), 0x143, 0xC, 0xF, true));
  return v;                                // lane l = sum of lanes 0..l
}
__device__ __forceinline__ float waveSum(float v){
  return readlanef(waveScanInc(v), 63);
}
__device__ __forceinline__ void waveArgmax(float &v, int &i){
#define AMSTEP(ctrl, rm) { \
    float ov = __int_as_float(__builtin_amdgcn_update_dpp(__float_as_int(v), __float_as_int(v), ctrl, rm, 0xF, false)); \
    int   oi = __builtin_amdgcn_update_dpp(i, i, ctrl, rm, 0xF, false); \
    bool take = (ov > v) || (ov == v && oi < i); \
    v = take ? ov : v; i = take ? oi : i; }
  AMSTEP(0x111, 0xF) AMSTEP(0x112, 0xF) AMSTEP(0x114, 0xF)
  AMSTEP(0x118, 0xF) AMSTEP(0x142, 0xA) AMSTEP(0x143, 0xC)
#undef AMSTEP
  v = readlanef(v, 63);
  i = __builtin_amdgcn_readlane(i, 63);
}
// paired gather: a = vec[idx], b = vec[idx+64] (0 outside [0,128)); 2 bpermutes total
__device__ __forceinline__ void gatherPair(float v0, float v1, int idx, float &a, float &b){
  int c = idx & 63;
  float g0 = __shfl(v0, c, 64);
  float g1 = __shfl(v1, c, 64);
  a = ((unsigned)idx < 128u) ? ((idx & 64) ? g1 : g0) : 0.f;
  int idx2 = idx + 64;
  b = ((unsigned)idx2 < 128u) ? ((idx2 & 64) ? g1 : g0) : 0.f;
}

// ---------- prep kernel (r5 version: 512 threads, K-quarter split, LDS combine) ----------
__global__ __launch_bounds__(512)
void prepK(const float* __restrict__ w1, const float* __restrict__ b1,
           const float* __restrict__ w2, const float* __restrict__ b2,
           float* __restrict__ M4, float* __restrict__ biasT, int* __restrict__ ticket){
  const int blk = blockIdx.x;
  const int tid = threadIdx.x;
  const int u = tid & 127, q = tid >> 7;   // u = output-row/col, q = K-quarter 0..3
  __shared__ float part[512];
  if (blk < 512){
    int i = blk >> 7, o = blk & 127;
    const float* w1p = w1 + (i * 256 + q * 64) * 128 + u;   // coalesced over d=u
    const float* w2p = w2 + o * 1024 + i * 256 + q * 64;    // wave-uniform
    float a0 = 0.f, a1 = 0.f, a2 = 0.f, a3 = 0.f;
    #pragma unroll
    for (int c = 0; c < 64; c += 4){
      a0 = fmaf(w1p[(c + 0) * 128], w2p[c + 0], a0);
      a1 = fmaf(w1p[(c + 1) * 128], w2p[c + 1], a1);
      a2 = fmaf(w1p[(c + 2) * 128], w2p[c + 2], a2);
      a3 = fmaf(w1p[(c + 3) * 128], w2p[c + 3], a3);
    }
    part[tid] = (a0 + a1) + (a2 + a3);
    __syncthreads();
    if (q == 0)
      M4[i * 16384 + (u >> 2) * 512 + o * 4 + (u & 3)] =
          (part[u] + part[128 + u]) + (part[256 + u] + part[384 + u]);
  } else if (blk < 516){
    int i = blk - 512;
    const float* w2p = w2 + u * 1024 + i * 256 + q * 64;
    const float* b1p = b1 + i * 256 + q * 64;
    float a0 = (q == 0) ? b2[u] : 0.f, a1 = 0.f, a2 = 0.f, a3 = 0.f;
    #pragma unroll
    for (int c = 0; c < 64; c += 4){
      a0 = fmaf(b1p[c + 0], w2p[c + 0], a0);
      a1 = fmaf(b1p[c + 1], w2p[c + 1], a1);
      a2 = fmaf(b1p[c + 2], w2p[c + 2], a2);
      a3 = fmaf(b1p[c + 3], w2p[c + 3], a3);
    }
    part[tid] = (a0 + a1) + (a2 + a3);
    __syncthreads();
    if (q == 0)
      biasT[i * 128 + u] = (part[u] + part[128 + u]) + (part[256 + u] + part[384 + u]);
  } else {
    if (tid == 0) *ticket = 0;
  }
}

// M-group load/consume macros — NAMED float4 scalars (no arrays: spill-proof).
// MpW is pre-offset per wave (j-half) and per thread (output o); local group gg 0..3.
#define MLD(d0, d1, d2, d3, gg) \
  d0 = MpW[((gg) * 4 + 0) * 128]; d1 = MpW[((gg) * 4 + 1) * 128]; \
  d2 = MpW[((gg) * 4 + 2) * 128]; d3 = MpW[((gg) * 4 + 3) * 128];
#define MFM(m0, m1, m2, m3, src, kb) \
  a0 = fmaf((m0).x, readlanef(src, (kb) + 0), a0);  a0 = fmaf((m0).y, readlanef(src, (kb) + 1), a0); \
  a0 = fmaf((m0).z, readlanef(src, (kb) + 2), a0);  a0 = fmaf((m0).w, readlanef(src, (kb) + 3), a0); \
  a1 = fmaf((m1).x, readlanef(src, (kb) + 4), a1);  a1 = fmaf((m1).y, readlanef(src, (kb) + 5), a1); \
  a1 = fmaf((m1).z, readlanef(src, (kb) + 6), a1);  a1 = fmaf((m1).w, readlanef(src, (kb) + 7), a1); \
  a2 = fmaf((m2).x, readlanef(src, (kb) + 8), a2);  a2 = fmaf((m2).y, readlanef(src, (kb) + 9), a2); \
  a2 = fmaf((m2).z, readlanef(src, (kb) +10), a2);  a2 = fmaf((m2).w, readlanef(src, (kb) +11), a2); \
  a3 = fmaf((m3).x, readlanef(src, (kb) +12), a3);  a3 = fmaf((m3).y, readlanef(src, (kb) +13), a3); \
  a3 = fmaf((m3).z, readlanef(src, (kb) +14), a3);  a3 = fmaf((m3).w, readlanef(src, (kb) +15), a3);

// ---------- main kernel: r4 structure (verified passing), launch bounds FIXED ----------
// r4's ONLY diagnosed defect was __launch_bounds__(256,8): 64-VGPR ceiling -> allocator
// dropped to 32 VGPR and spilled all 8 MLP float4 buffers to scratch (FETCH/WRITE 4.2MB).
// (256,4) caps at 128 VGPR; kernel needs ~60-75 -> no spill, and the grid's 8192 waves
// then give 28-32 waves/CU (vs 16 for the 2-wave layout).
// wave w = 2*jh + th : th = t-half (t = 64*th + l), jh = j-half (j in [64*jh, 64*jh+64)).
// Window value (t, j) = ydW[w][(255 - t) + j] where ydW[w][128+k] = ydW[w][256+k] = y_res[k]
// (per-wave private copy -> no end-of-iteration barrier).
__global__ __launch_bounds__(256, 4)
void mainK(const float* __restrict__ x, const float* __restrict__ y,
           const float* __restrict__ M4, const float* __restrict__ biasT,
           unsigned long long* __restrict__ partials, int* __restrict__ ticket,
           float* __restrict__ out){
  __shared__ float ydW[4][384];   // per-wave y window copies
  __shared__ float Ab[64], Bb[64], Cb[64], Db[64], Pb[64], Qb[64];  // corr partials
  __shared__ float mlpB[256];     // MLP half-partials: [o]=low-k, [128+o]=high-k
  __shared__ float sL[4], sC[4];
  __shared__ int   sOld;

  const int u  = threadIdx.x;     // 0..255
  const int l  = u & 63;
  const int w  = u >> 6;          // wave 0..3
  const int th = w & 1;           // t-half
  const int jh = w >> 1;          // j-half (also MLP k-half)
  const int o  = u & 127;         // MLP output index
  const long base = (long)blockIdx.x * 128;

  float xlo = x[base + l], xhi = x[base + 64 + l];
  float ylo = y[base + l], yhi = y[base + 64 + l];
  const bool mask_l = (ylo == IGNORE_OUT);
  const bool mask_h = (yhi == IGNORE_OUT);
  float cnt = (w == 0) ? (mask_l ? 0.f : 1.f) : ((w == 1) ? (mask_h ? 0.f : 1.f) : 0.f);
  float lossAcc = 0.f;

  // own-wave window copy (same-wave RAW via LDS: no barrier needed)
  float* ydw = ydW[w];
  ydw[128 + l] = ylo; ydw[192 + l] = yhi; ydw[256 + l] = ylo; ydw[320 + l] = yhi;
  const float* wp = ydw + (255 - 64 * th + 64 * jh) - l;   // quadrant window base

  for (int i = 0; i < NITER; ++i){
    const float4* MpW = (const float4*)(M4 + (size_t)i * 16384) + jh * 2048 + o;
    float bias_l = biasT[i * 128 + l];          // both halves' bias (phase D)
    float bias_h = biasT[i * 128 + 64 + l];

    // ---- phase A: corr quadrant (64 b32 LDS reads, readlane broadcasts, 4-way split;
    //      masked prefix only on diagonal waves 0,3) + scans (dup, all waves) ----
    const float xsrc = jh ? xhi : xlo;
    float s0=0.f,s1=0.f,s2=0.f,s3=0.f, p0=0.f,p1=0.f,p2=0.f,p3=0.f;
    if (w == 0 || w == 3){
      #pragma unroll
      for (int j = 0; j < 64; j += 4){
        float wv0 = wp[j], wv1 = wp[j+1], wv2 = wp[j+2], wv3 = wp[j+3];
        float x0 = readlanef(xsrc, j),   x1 = readlanef(xsrc, j+1);
        float x2 = readlanef(xsrc, j+2), x3 = readlanef(xsrc, j+3);
        s0 = fmaf(wv0, x0, s0); s1 = fmaf(wv1, x1, s1);
        s2 = fmaf(wv2, x2, s2); s3 = fmaf(wv3, x3, s3);
        p0 = fmaf((l >= j    ) ? wv0 : 0.f, x0, p0);
        p1 = fmaf((l >= j + 1) ? wv1 : 0.f, x1, p1);
        p2 = fmaf((l >= j + 2) ? wv2 : 0.f, x2, p2);
        p3 = fmaf((l >= j + 3) ? wv3 : 0.f, x3, p3);
      }
    } else {
      #pragma unroll
      for (int j = 0; j < 64; j += 4){
        float wv0 = wp[j], wv1 = wp[j+1], wv2 = wp[j+2], wv3 = wp[j+3];
        s0 = fmaf(wv0, readlanef(xsrc, j),   s0);
        s1 = fmaf(wv1, readlanef(xsrc, j+1), s1);
        s2 = fmaf(wv2, readlanef(xsrc, j+2), s2);
        s3 = fmaf(wv3, readlanef(xsrc, j+3), s3);
      }
    }
    float S = (s0 + s1) + (s2 + s3);
    float P = (p0 + p1) + (p2 + p3);
    if      (w == 0){ Ab[l] = S; Pb[l] = P; }
    else if (w == 1){ Bb[l] = S; }
    else if (w == 2){ Cb[l] = S; }
    else            { Db[l] = S; Qb[l] = P; }

    // scans (duplicated in every wave; identical arithmetic to r3 per t-half)
    float v_lo = waveScanInc(xlo * xlo);
    float slo  = readlanef(v_lo, 63);
    float v_hi = waveScanInc(xhi * xhi);
    float shi  = readlanef(v_hi, 63);
    float total = slo + shi;
    float ny2 = waveSum(ylo * ylo + yhi * yhi);

    __syncthreads();                       // B_a: corr partials visible

    // ---- phase B: all waves compute all 256 sims + full argmax in-wave ----
    float SA = Ab[l], SB = Bb[l], SC = Cb[l], SD = Db[l], PP = Pb[l], QQ = Qb[l];
    float nt_l = SA + SC, n1_l = PP;        // t = l
    float nt_h = SB + SD, n1_h = SB + QQ;   // t = 64 + l
    float pref_l = v_lo;                    // inclusive x^2 prefix at t=l
    float pref_h = v_hi + slo;              // at t=64+l (same grouping as r3)
    int sstar;
    {
      bool yz = (ny2 == 0.f);
      float rNY = __builtin_amdgcn_rsqf(ny2);
      float nx_l = fmaxf(total - pref_l, 0.f);
      float nx_h = fmaxf(total - pref_h, 0.f);
      float s1l = (yz || pref_l == 0.f) ? 0.f : n1_l * __builtin_amdgcn_rsqf(pref_l) * rNY;
      float s2l = (yz || nx_l   == 0.f) ? 0.f : (nt_l - n1_l) * __builtin_amdgcn_rsqf(nx_l) * rNY;
      float s1h = (yz || pref_h == 0.f) ? 0.f : n1_h * __builtin_amdgcn_rsqf(pref_h) * rNY;
      float s2h = (yz || nx_h   == 0.f) ? 0.f : (nt_h - n1_h) * __builtin_amdgcn_rsqf(nx_h) * rNY;
      if (l == 63) s2h = -INFINITY;        // shift 255 doesn't exist
      // 4 candidates in increasing shift order -> strict > keeps first-max semantics
      float bv = s1l; int bi = l;
      if (s1h > bv){ bv = s1h; bi = 64 + l; }
      if (s2l > bv){ bv = s2l; bi = 128 + l; }
      if (s2h > bv){ bv = s2h; bi = 192 + l; }
      waveArgmax(bv, bi);
      sstar = bi;
    }

    // ---- MLP prefetch (this wave's k-half, groups 0,1): hidden under softmax ----
    float4 A0, A1, A2, A3, B0, B1, B2, B3;
    MLD(A0, A1, A2, A3, 0)
    MLD(B0, B1, B2, B3, 1)

    // ---- x_aug + detached softmax + x_res update (duplicated in every wave) ----
    float xa, xb;
    gatherPair(xlo, xhi, sstar + l - 127, xa, xb);
    float ea = __builtin_amdgcn_exp2f(xa * ylo * LOG2E);
    float eb = __builtin_amdgcn_exp2f(xb * yhi * LOG2E);
    float rse = __builtin_amdgcn_rcpf(waveSum(ea + eb));
    float wlo = xa * (ea * rse), whi = xb * (eb * rse);   // xatt
    {
      float ga, gb;
      gatherPair(wlo, whi, l + 127 - sstar, ga, gb);
      xlo -= ga; xhi -= gb;
    }

    // ---- phase C: MLP half-dot (64 k's), 2 rotating buffers ----
    {
      const float wsrc = jh ? whi : wlo;
      float a0 = 0.f, a1 = 0.f, a2 = 0.f, a3 = 0.f;
      MFM(A0, A1, A2, A3, wsrc, 0)   MLD(A0, A1, A2, A3, 2)
      MFM(B0, B1, B2, B3, wsrc, 16)  MLD(B0, B1, B2, B3, 3)
      MFM(A0, A1, A2, A3, wsrc, 32)
      MFM(B0, B1, B2, B3, wsrc, 48)
      mlpB[u] = (a0 + a1) + (a2 + a3);
    }
    __syncthreads();                       // B_c: MLP partials visible

    // ---- phase D: every thread combines ye for BOTH its elements; owners do loss;
    //      each wave refreshes its own window copy (no trailing barrier) ----
    {
      float ye_l = (mlpB[l]      + mlpB[128 + l]) + bias_l;
      float ye_h = (mlpB[64 + l] + mlpB[192 + l]) + bias_h;
      float df_l = ye_l - ylo, df_h = ye_h - yhi;
      if (w == 0 && !mask_l) lossAcc = fmaf(df_l, df_l, lossAcc);
      if (w == 1 && !mask_h) lossAcc = fmaf(df_h, df_h, lossAcc);
      ylo -= ye_l; yhi -= ye_h;
      ydw[128 + l] = ylo; ydw[192 + l] = yhi; ydw[256 + l] = ylo; ydw[320 + l] = yhi;
    }
  }

  // ---- block loss/cnt, partial store + ticket; last block finalizes ----
  lossAcc = waveSum(lossAcc);
  cnt     = waveSum(cnt);
  if (l == 0){ sL[w] = lossAcc; sC[w] = cnt; }
  __syncthreads();
  if (u == 0){
    union { float2 f; unsigned long long v; } pk;
    pk.f.x = (sL[0] + sL[1]) + (sL[2] + sL[3]);
    pk.f.y = (sC[0] + sC[1]) + (sC[2] + sC[3]);
    __hip_atomic_store(&partials[blockIdx.x], pk.v, __ATOMIC_RELEASE, __HIP_MEMORY_SCOPE_AGENT);
    sOld = __hip_atomic_fetch_add(ticket, 1, __ATOMIC_ACQ_REL, __HIP_MEMORY_SCOPE_AGENT);
  }
  __syncthreads();
  if (sOld == NBLK - 1){
    float ls = 0.f, cs = 0.f;
    for (int g = u; g < NBLK; g += 256){
      union { float2 f; unsigned long long v; } pk;
      pk.v = __hip_atomic_load(&partials[g], __ATOMIC_ACQUIRE, __HIP_MEMORY_SCOPE_AGENT);
      ls += pk.f.x; cs += pk.f.y;
    }
    ls = waveSum(ls); cs = waveSum(cs);
    if (l == 0){ sL[w] = ls; sC[w] = cs; }
    __syncthreads();
    if (u == 0) out[0] = ((sL[0] + sL[1]) + (sL[2] + sL[3])) /
                         ((float)NITER * ((sC[0] + sC[1]) + (sC[2] + sC[3])));
  }
}

extern "C" void kernel_launch(void* const* d_in, const int* in_sizes, int n_in,
                              void* d_out, int out_size, void* d_ws, size_t ws_size,
                              hipStream_t stream){
  const float* x  = (const float*)d_in[0];
  const float* y  = (const float*)d_in[1];
  const float* w1 = (const float*)d_in[2];
  const float* b1 = (const float*)d_in[3];
  const float* w2 = (const float*)d_in[4];
  const float* b2 = (const float*)d_in[5];
  float* out = (float*)d_out;

  // ws: [0,4) ticket ; [256, 256+256K) M4 ; +2K biasT ; +16K partials
  int*   ticket = (int*)d_ws;
  float* M4     = (float*)((char*)d_ws + 256);
  float* biasT  = (float*)((char*)d_ws + 256 + 4 * 128 * 128 * sizeof(float));
  unsigned long long* partials =
      (unsigned long long*)((char*)d_ws + 256 + 4 * 128 * 128 * sizeof(float) + 4 * 128 * sizeof(float));

  prepK<<<517, 512, 0, stream>>>(w1, b1, w2, b2, M4, biasT, ticket);
  mainK<<<NBLK, 256, 0, stream>>>(x, y, M4, biasT, partials, ticket, out);
}

// Round 8
// 155.429 us; speedup vs baseline: 1.1336x; 1.0344x over previous
//
#include <hip/hip_runtime.h>
#include <math.h>

// B=4, T=512, IDIM=128, HDIM=1024, CDIM=256
#define NBLK  2048            // one row per block, ONE wave per block (barrier-free)
#define NITER 4
#define IGNORE_OUT 10000.0f
#define LOG2E 1.44269504088896340736f

__device__ __forceinline__ float readlanef(float v, int lane){
  return __int_as_float(__builtin_amdgcn_readlane(__float_as_int(v), lane));
}

// ---- DPP wave primitives (gfx9 ladder: row_shr 1/2/4/8, bcast15->rows1,3, bcast31->rows2,3) ----
__device__ __forceinline__ float waveScanInc(float v){
  v += __int_as_float(__builtin_amdgcn_update_dpp(0, __float_as_int(v), 0x111, 0xF, 0xF, true));
  v += __int_as_float(__builtin_amdgcn_update_dpp(0, __float_as_int(v), 0x112, 0xF, 0xF, true));
  v += __int_as_float(__builtin_amdgcn_update_dpp(0, __float_as_int(v), 0x114, 0xF, 0xF, true));
  v += __int_as_float(__builtin_amdgcn_update_dpp(0, __float_as_int(v), 0x118, 0xF, 0xF, true));
  v += __int_as_float(__builtin_amdgcn_update_dpp(0, __float_as_int(v), 0x142, 0xA, 0xF, true));
  v += __int_as_float(__builtin_amdgcn_update_dpp(0, __float_as_int(v), 0x143, 0xC, 0xF, true));
  return v;                                // lane l = sum of lanes 0..l
}
__device__ __forceinline__ float waveSum(float v){
  return readlanef(waveScanInc(v), 63);
}
__device__ __forceinline__ void waveArgmax(float &v, int &i){
#define AMSTEP(ctrl, rm) { \
    float ov = __int_as_float(__builtin_amdgcn_update_dpp(__float_as_int(v), __float_as_int(v), ctrl, rm, 0xF, false)); \
    int   oi = __builtin_amdgcn_update_dpp(i, i, ctrl, rm, 0xF, false); \
    bool take = (ov > v) || (ov == v && oi < i); \
    v = take ? ov : v; i = take ? oi : i; }
  AMSTEP(0x111, 0xF) AMSTEP(0x112, 0xF) AMSTEP(0x114, 0xF)
  AMSTEP(0x118, 0xF) AMSTEP(0x142, 0xA) AMSTEP(0x143, 0xC)
#undef AMSTEP
  v = readlanef(v, 63);
  i = __builtin_amdgcn_readlane(i, 63);
}
// paired gather: a = vec[idx], b = vec[idx+64] (0 outside [0,128)); 2 bpermutes total
__device__ __forceinline__ void gatherPair(float v0, float v1, int idx, float &a, float &b){
  int c = idx & 63;
  float g0 = __shfl(v0, c, 64);
  float g1 = __shfl(v1, c, 64);
  a = ((unsigned)idx < 128u) ? ((idx & 64) ? g1 : g0) : 0.f;
  int idx2 = idx + 64;
  b = ((unsigned)idx2 < 128u) ? ((idx2 & 64) ? g1 : g0) : 0.f;
}

// ---------- prep kernel (r5 version: 512 threads, K-quarter split, LDS combine) ----------
__global__ __launch_bounds__(512)
void prepK(const float* __restrict__ w1, const float* __restrict__ b1,
           const float* __restrict__ w2, const float* __restrict__ b2,
           float* __restrict__ M4, float* __restrict__ biasT, int* __restrict__ ticket){
  const int blk = blockIdx.x;
  const int tid = threadIdx.x;
  const int u = tid & 127, q = tid >> 7;   // u = output-row/col, q = K-quarter 0..3
  __shared__ float part[512];
  if (blk < 512){
    int i = blk >> 7, o = blk & 127;
    const float* w1p = w1 + (i * 256 + q * 64) * 128 + u;   // coalesced over d=u
    const float* w2p = w2 + o * 1024 + i * 256 + q * 64;    // wave-uniform
    float a0 = 0.f, a1 = 0.f, a2 = 0.f, a3 = 0.f;
    #pragma unroll
    for (int c = 0; c < 64; c += 4){
      a0 = fmaf(w1p[(c + 0) * 128], w2p[c + 0], a0);
      a1 = fmaf(w1p[(c + 1) * 128], w2p[c + 1], a1);
      a2 = fmaf(w1p[(c + 2) * 128], w2p[c + 2], a2);
      a3 = fmaf(w1p[(c + 3) * 128], w2p[c + 3], a3);
    }
    part[tid] = (a0 + a1) + (a2 + a3);
    __syncthreads();
    if (q == 0)
      M4[i * 16384 + (u >> 2) * 512 + o * 4 + (u & 3)] =
          (part[u] + part[128 + u]) + (part[256 + u] + part[384 + u]);
  } else if (blk < 516){
    int i = blk - 512;
    const float* w2p = w2 + u * 1024 + i * 256 + q * 64;
    const float* b1p = b1 + i * 256 + q * 64;
    float a0 = (q == 0) ? b2[u] : 0.f, a1 = 0.f, a2 = 0.f, a3 = 0.f;
    #pragma unroll
    for (int c = 0; c < 64; c += 4){
      a0 = fmaf(b1p[c + 0], w2p[c + 0], a0);
      a1 = fmaf(b1p[c + 1], w2p[c + 1], a1);
      a2 = fmaf(b1p[c + 2], w2p[c + 2], a2);
      a3 = fmaf(b1p[c + 3], w2p[c + 3], a3);
    }
    part[tid] = (a0 + a1) + (a2 + a3);
    __syncthreads();
    if (q == 0)
      biasT[i * 128 + u] = (part[u] + part[128 + u]) + (part[256 + u] + part[384 + u]);
  } else {
    if (tid == 0) *ticket = 0;
  }
}

// ---- MLP macros: dual-output (o=l and o=64+l), NAMED float4 scalars only ----
// Group gg = M float4-rows 4gg..4gg+3 = k-values 16gg..16gg+15; per-output accumulation
// order identical to the r3-verified MFM (a0: k%16 in 0..3, a1: 4..7, ...).
#define MLD2(pa,pb,pc,pd, qa,qb,qc,qd, gg) \
  pa = MpL[((gg)*4+0)*128]; pb = MpL[((gg)*4+1)*128]; pc = MpL[((gg)*4+2)*128]; pd = MpL[((gg)*4+3)*128]; \
  qa = MpH[((gg)*4+0)*128]; qb = MpH[((gg)*4+1)*128]; qc = MpH[((gg)*4+2)*128]; qd = MpH[((gg)*4+3)*128];
#define MFM2(pa,pb,pc,pd, qa,qb,qc,qd, gg) { \
  float4 xA = XW[4*(gg)+0], xB = XW[4*(gg)+1], xC = XW[4*(gg)+2], xD = XW[4*(gg)+3]; \
  a0=fmaf((pa).x,xA.x,a0); a0=fmaf((pa).y,xA.y,a0); a0=fmaf((pa).z,xA.z,a0); a0=fmaf((pa).w,xA.w,a0); \
  a1=fmaf((pb).x,xB.x,a1); a1=fmaf((pb).y,xB.y,a1); a1=fmaf((pb).z,xB.z,a1); a1=fmaf((pb).w,xB.w,a1); \
  a2=fmaf((pc).x,xC.x,a2); a2=fmaf((pc).y,xC.y,a2); a2=fmaf((pc).z,xC.z,a2); a2=fmaf((pc).w,xC.w,a2); \
  a3=fmaf((pd).x,xD.x,a3); a3=fmaf((pd).y,xD.y,a3); a3=fmaf((pd).z,xD.z,a3); a3=fmaf((pd).w,xD.w,a3); \
  b0=fmaf((qa).x,xA.x,b0); b0=fmaf((qa).y,xA.y,b0); b0=fmaf((qa).z,xA.z,b0); b0=fmaf((qa).w,xA.w,b0); \
  b1=fmaf((qb).x,xB.x,b1); b1=fmaf((qb).y,xB.y,b1); b1=fmaf((qb).z,xB.z,b1); b1=fmaf((qb).w,xB.w,b1); \
  b2=fmaf((qc).x,xC.x,b2); b2=fmaf((qc).y,xC.y,b2); b2=fmaf((qc).z,xC.z,b2); b2=fmaf((qc).w,xC.w,b2); \
  b3=fmaf((qd).x,xD.x,b3); b3=fmaf((qd).y,xD.y,b3); b3=fmaf((qd).z,xD.z,b3); b3=fmaf((qd).w,xD.w,b3); }

// ---------- main kernel: ONE WAVE PER ROW, zero barriers in the iteration loop ----------
// Lane l owns elements l and 64+l; the wave computes all 255 shifts itself:
//   shift candidates per lane: t=l, t=64+l (s1 form) and t+128 (s2 form) -> r4's
//   verified 4-candidate in-wave argmax.
// Window reads: Wk[k] = yd[191-l+k], k=0..191; W_h[j]=Wk[j], W_l[j]=Wk[64+j]
//   (middle 64 values shared between the two windows -> read once).
// x broadcasts: wave-private LDS buffer read at wave-uniform address (float4) = free
//   broadcast, replacing v_readlane. Corr accumulation order per-accumulator is
//   bit-identical to the r3/r4-verified split (s/t/p per t-half).
__global__ __launch_bounds__(64, 2)
void mainK(const float* __restrict__ x, const float* __restrict__ y,
           const float* __restrict__ M4, const float* __restrict__ biasT,
           unsigned long long* __restrict__ partials, int* __restrict__ ticket,
           float* __restrict__ out){
  __shared__ float yd[384];     // private y window: yd[128+k] = yd[256+k] = y_res[k]
  __shared__ float xsB[128];    // private x_res broadcast buffer
  __shared__ float xwB[128];    // private x_attn broadcast buffer

  const int l = threadIdx.x;    // 0..63
  const long base = (long)blockIdx.x * 128;

  float xlo = x[base + l], xhi = x[base + 64 + l];
  float ylo = y[base + l], yhi = y[base + 64 + l];
  const bool mask_l = (ylo == IGNORE_OUT);
  const bool mask_h = (yhi == IGNORE_OUT);
  float cntL = mask_l ? 0.f : 1.f, cntH = mask_h ? 0.f : 1.f;
  float lossL = 0.f, lossH = 0.f;

  yd[128 + l] = ylo; yd[192 + l] = yhi; yd[256 + l] = ylo; yd[320 + l] = yhi;
  const float*  Wp = yd + (191 - l);           // Wk base (191-l in [128,191], max idx 382)
  const float4* XS = (const float4*)xsB;
  const float4* XW = (const float4*)xwB;

  for (int i = 0; i < NITER; ++i){
    const float4* Mp  = (const float4*)(M4 + (size_t)i * 16384);
    const float4* MpL = Mp + l;                // output o = l
    const float4* MpH = Mp + 64 + l;           // output o = 64+l

    // publish x_res broadcast copy (same-wave RAW via lgkmcnt; NO barrier)
    xsB[l] = xlo; xsB[64 + l] = xhi;

    // ---- scans (DPP only; same grouping as r4) ----
    float v_lo = waveScanInc(xlo * xlo);
    float slo  = readlanef(v_lo, 63);
    float v_hi = waveScanInc(xhi * xhi);
    float shi  = readlanef(v_hi, 63);
    float total = slo + shi;
    float ny2 = waveSum(ylo * ylo + yhi * yhi);

    // ---- corr: both shift-candidates of this lane in one fused loop.
    //      s/t/p: t=l (first-half full, second-half full, first-half masked prefix)
    //      u/w/q: t=64+l (first-half full, second-half full, second-half masked prefix)
    //      g1 (the shared middle window third) feeds both. ----
    float s0=0.f,s1=0.f,s2=0.f,s3=0.f, t0=0.f,t1=0.f,t2=0.f,t3=0.f, p0=0.f,p1=0.f,p2=0.f,p3=0.f;
    float u0=0.f,u1=0.f,u2=0.f,u3=0.f, w0=0.f,w1=0.f,w2=0.f,w3=0.f, q0=0.f,q1=0.f,q2=0.f,q3=0.f;
    #pragma unroll
    for (int m = 0; m < 16; ++m){
      float4 xvA = XS[m];        // x_res[4m .. 4m+3]
      float4 xvB = XS[16 + m];   // x_res[64+4m .. 64+4m+3]
      float g0a=Wp[4*m+0],  g0b=Wp[4*m+1],  g0c=Wp[4*m+2],  g0d=Wp[4*m+3];     // W_h 1st half
      float g1a=Wp[64+4*m], g1b=Wp[65+4*m], g1c=Wp[66+4*m], g1d=Wp[67+4*m];    // shared third
      float g2a=Wp[128+4*m],g2b=Wp[129+4*m],g2c=Wp[130+4*m],g2d=Wp[131+4*m];   // W_l 2nd half
      const int jb = 4 * m;
      // t = 64+l, first half (full)
      u0=fmaf(g0a,xvA.x,u0); u1=fmaf(g0b,xvA.y,u1); u2=fmaf(g0c,xvA.z,u2); u3=fmaf(g0d,xvA.w,u3);
      // t = l, first half (full + masked prefix)
      s0=fmaf(g1a,xvA.x,s0); s1=fmaf(g1b,xvA.y,s1); s2=fmaf(g1c,xvA.z,s2); s3=fmaf(g1d,xvA.w,s3);
      p0=fmaf((l>=jb  )?g1a:0.f, xvA.x, p0); p1=fmaf((l>=jb+1)?g1b:0.f, xvA.y, p1);
      p2=fmaf((l>=jb+2)?g1c:0.f, xvA.z, p2); p3=fmaf((l>=jb+3)?g1d:0.f, xvA.w, p3);
      // t = 64+l, second half (full + masked prefix; same g1 values, x from 2nd half)
      w0=fmaf(g1a,xvB.x,w0); w1=fmaf(g1b,xvB.y,w1); w2=fmaf(g1c,xvB.z,w2); w3=fmaf(g1d,xvB.w,w3);
      q0=fmaf((l>=jb  )?g1a:0.f, xvB.x, q0); q1=fmaf((l>=jb+1)?g1b:0.f, xvB.y, q1);
      q2=fmaf((l>=jb+2)?g1c:0.f, xvB.z, q2); q3=fmaf((l>=jb+3)?g1d:0.f, xvB.w, q3);
      // t = l, second half (full)
      t0=fmaf(g2a,xvB.x,t0); t1=fmaf(g2b,xvB.y,t1); t2=fmaf(g2c,xvB.z,t2); t3=fmaf(g2d,xvB.w,t3);
    }
    float Sh0_l=(s0+s1)+(s2+s3), Sh1_l=(t0+t1)+(t2+t3), P=(p0+p1)+(p2+p3);
    float Sh0_h=(u0+u1)+(u2+u3), Sh1_h=(w0+w1)+(w2+w3), Q=(q0+q1)+(q2+q3);
    float nt_l = Sh0_l + Sh1_l, n1_l = P;
    float nt_h = Sh0_h + Sh1_h, n1_h = Sh0_h + Q;
    float pref_l = v_lo;
    float pref_h = v_hi + slo;

    // ---- sims + full in-wave argmax (r4's verified 4-candidate form) ----
    int sstar;
    {
      bool yz = (ny2 == 0.f);
      float rNY = __builtin_amdgcn_rsqf(ny2);
      float nx_l = fmaxf(total - pref_l, 0.f);
      float nx_h = fmaxf(total - pref_h, 0.f);
      float s1l = (yz || pref_l == 0.f) ? 0.f : n1_l * __builtin_amdgcn_rsqf(pref_l) * rNY;
      float s2l = (yz || nx_l   == 0.f) ? 0.f : (nt_l - n1_l) * __builtin_amdgcn_rsqf(nx_l) * rNY;
      float s1h = (yz || pref_h == 0.f) ? 0.f : n1_h * __builtin_amdgcn_rsqf(pref_h) * rNY;
      float s2h = (yz || nx_h   == 0.f) ? 0.f : (nt_h - n1_h) * __builtin_amdgcn_rsqf(nx_h) * rNY;
      if (l == 63) s2h = -INFINITY;      // shift 255 doesn't exist
      float bv = s1l; int bi = l;
      if (s1h > bv){ bv = s1h; bi = 64 + l; }
      if (s2l > bv){ bv = s2l; bi = 128 + l; }
      if (s2h > bv){ bv = s2h; bi = 192 + l; }
      waveArgmax(bv, bi);
      sstar = bi;
    }

    // ---- issue MLP groups 0,1 (both outputs) + bias: hidden under softmax ----
    float4 P0,P1,P2,P3, Q0,Q1,Q2,Q3, R0,R1,R2,R3, S0,S1,S2,S3;
    MLD2(P0,P1,P2,P3, Q0,Q1,Q2,Q3, 0)
    MLD2(R0,R1,R2,R3, S0,S1,S2,S3, 1)
    float bias_l = biasT[i * 128 + l];
    float bias_h = biasT[i * 128 + 64 + l];

    // ---- x_aug + detached softmax (computed ONCE per row now) ----
    float xa, xb;
    gatherPair(xlo, xhi, sstar + l - 127, xa, xb);
    float ea = __builtin_amdgcn_exp2f(xa * ylo * LOG2E);
    float eb = __builtin_amdgcn_exp2f(xb * yhi * LOG2E);
    float rse = __builtin_amdgcn_rcpf(waveSum(ea + eb));
    float wlo = xa * (ea * rse), whi = xb * (eb * rse);   // xatt

    // ---- x_res update (reverse shift) ----
    {
      float ga, gb;
      gatherPair(wlo, whi, l + 127 - sstar, ga, gb);
      xlo -= ga; xhi -= gb;
    }

    // publish x_attn broadcast copy (same-wave RAW)
    xwB[l] = wlo; xwB[64 + l] = whi;

    // ---- MLP: both outputs, 2 rotating dual buffers, 1-group-ahead prefetch ----
    float ye_l, ye_h;
    {
      float a0=0.f,a1=0.f,a2=0.f,a3=0.f, b0=0.f,b1=0.f,b2=0.f,b3=0.f;
      MFM2(P0,P1,P2,P3, Q0,Q1,Q2,Q3, 0)  MLD2(P0,P1,P2,P3, Q0,Q1,Q2,Q3, 2)
      MFM2(R0,R1,R2,R3, S0,S1,S2,S3, 1)  MLD2(R0,R1,R2,R3, S0,S1,S2,S3, 3)
      MFM2(P0,P1,P2,P3, Q0,Q1,Q2,Q3, 2)  MLD2(P0,P1,P2,P3, Q0,Q1,Q2,Q3, 4)
      MFM2(R0,R1,R2,R3, S0,S1,S2,S3, 3)  MLD2(R0,R1,R2,R3, S0,S1,S2,S3, 5)
      MFM2(P0,P1,P2,P3, Q0,Q1,Q2,Q3, 4)  MLD2(P0,P1,P2,P3, Q0,Q1,Q2,Q3, 6)
      MFM2(R0,R1,R2,R3, S0,S1,S2,S3, 5)  MLD2(R0,R1,R2,R3, S0,S1,S2,S3, 7)
      MFM2(P0,P1,P2,P3, Q0,Q1,Q2,Q3, 6)
      MFM2(R0,R1,R2,R3, S0,S1,S2,S3, 7)
      ye_l = ((a0 + a1) + (a2 + a3)) + bias_l;
      ye_h = ((b0 + b1) + (b2 + b3)) + bias_h;
    }

    // ---- loss + y_res update + window refresh (all wave-private; NO barrier) ----
    {
      float df_l = ye_l - ylo, df_h = ye_h - yhi;
      if (!mask_l) lossL = fmaf(df_l, df_l, lossL);
      if (!mask_h) lossH = fmaf(df_h, df_h, lossH);
      ylo -= ye_l; yhi -= ye_h;
      yd[128 + l] = ylo; yd[192 + l] = yhi; yd[256 + l] = ylo; yd[320 + l] = yhi;
    }
  }

  // ---- row loss/cnt (order matches r3: elements 0..63 summed, then 64..127) ----
  float lsRow = waveSum(lossL) + waveSum(lossH);
  float csRow = waveSum(cntL)  + waveSum(cntH);
  int old = 0;
  if (l == 0){
    union { float2 f; unsigned long long v; } pk;
    pk.f.x = lsRow; pk.f.y = csRow;
    __hip_atomic_store(&partials[blockIdx.x], pk.v, __ATOMIC_RELEASE, __HIP_MEMORY_SCOPE_AGENT);
    old = __hip_atomic_fetch_add(ticket, 1, __ATOMIC_ACQ_REL, __HIP_MEMORY_SCOPE_AGENT);
  }
  old = __shfl(old, 0, 64);
  if (old == NBLK - 1){
    float ls = 0.f, cs = 0.f;
    for (int g = l; g < NBLK; g += 64){
      union { float2 f; unsigned long long v; } pk;
      pk.v = __hip_atomic_load(&partials[g], __ATOMIC_ACQUIRE, __HIP_MEMORY_SCOPE_AGENT);
      ls += pk.f.x; cs += pk.f.y;
    }
    ls = waveSum(ls); cs = waveSum(cs);
    if (l == 0) out[0] = ls / ((float)NITER * cs);
  }
}

extern "C" void kernel_launch(void* const* d_in, const int* in_sizes, int n_in,
                              void* d_out, int out_size, void* d_ws, size_t ws_size,
                              hipStream_t stream){
  const float* x  = (const float*)d_in[0];
  const float* y  = (const float*)d_in[1];
  const float* w1 = (const float*)d_in[2];
  const float* b1 = (const float*)d_in[3];
  const float* w2 = (const float*)d_in[4];
  const float* b2 = (const float*)d_in[5];
  float* out = (float*)d_out;

  // ws: [0,4) ticket ; [256, 256+256K) M4 ; +2K biasT ; +16K partials
  int*   ticket = (int*)d_ws;
  float* M4     = (float*)((char*)d_ws + 256);
  float* biasT  = (float*)((char*)d_ws + 256 + 4 * 128 * 128 * sizeof(float));
  unsigned long long* partials =
      (unsigned long long*)((char*)d_ws + 256 + 4 * 128 * 128 * sizeof(float) + 4 * 128 * sizeof(float));

  prepK<<<517, 512, 0, stream>>>(w1, b1, w2, b2, M4, biasT, ticket);
  mainK<<<NBLK, 64, 0, stream>>>(x, y, M4, biasT, partials, ticket, out);
}